// Round 5
// baseline (4784.004 us; speedup 1.0000x reference)
//
#include <hip/hip_runtime.h>
#include <stdint.h>

typedef _Float16 half2v __attribute__((ext_vector_type(2)));

__device__ __forceinline__ float sigf(float x) {
    return __builtin_amdgcn_rcpf(1.0f + __expf(-x));
}
__device__ __forceinline__ float tanhf_fast(float x) {
    return 1.0f - 2.0f * __builtin_amdgcn_rcpf(1.0f + __expf(2.0f * x));
}
__device__ __forceinline__ uint32_t pk2(float a, float b) {
    uint16_t ua = __builtin_bit_cast(uint16_t, (_Float16)a);
    uint16_t ub = __builtin_bit_cast(uint16_t, (_Float16)b);
    return (uint32_t)ua | ((uint32_t)ub << 16);
}
__device__ __forceinline__ float f16u(uint16_t b) {
    return (float)__builtin_bit_cast(_Float16, b);
}
__device__ __forceinline__ float dot2(uint32_t w, uint32_t h, float acc) {
#if __has_builtin(__builtin_amdgcn_fdot2)
    return __builtin_amdgcn_fdot2(__builtin_bit_cast(half2v, w),
                                  __builtin_bit_cast(half2v, h), acc, false);
#else
    asm("v_fma_mix_f32 %0, %1, %2, %0 op_sel:[0,0,0] op_sel_hi:[1,1,0]"
        : "+v"(acc) : "v"(w), "v"(h));
    asm("v_fma_mix_f32 %0, %1, %2, %0 op_sel:[1,1,0] op_sel_hi:[1,1,0]"
        : "+v"(acc) : "v"(w), "v"(h));
    return acc;
#endif
}

#define DOT4(acc, wv, hv)            \
    acc = dot2(wv.x, hv.x, acc);     \
    acc = dot2(wv.y, hv.y, acc);     \
    acc = dot2(wv.z, hv.z, acc);     \
    acc = dot2(wv.w, hv.w, acc);

__device__ __forceinline__ uint4 pack8(const float* s) {
    uint4 p;
    p.x = pk2(s[0], s[1]); p.y = pk2(s[2], s[3]);
    p.z = pk2(s[4], s[5]); p.w = pk2(s[6], s[7]);
    return p;
}

// Fused 2-layer LSTM encoder (persistent, T=1024) + decoder tail.
// grid = 256 blocks (1/CU), block = 1024 thr (16 waves -> 4 waves/SIMD).
// Thread (s = tid>>8, r = tid&255) owns gate row r's weights IN REGISTERS
// and computes row r for sample s only (96 dot2/step). Update role:
// threads 0..255, (j = tid&63, sq = tid>>6) own unit j of sample sq.
// 3 barriers/step via pre1/pre2 ping-pong.
// NOTE: second launch_bounds arg is CUDA-style min BLOCKS per CU on hipcc
// (R2/R4 counter evidence: (512,2)->VGPR 120 cap-128; (1024,4)->VGPR 64 spill).
// (1024,1) => 16 waves/CU = 4 waves/SIMD, VGPR cap 128, no spill.
__global__ __launch_bounds__(1024, 1)
void lstm_fused(const float* __restrict__ x,
                const float* __restrict__ W1i, const float* __restrict__ W1h,
                const float* __restrict__ b1i, const float* __restrict__ b1h,
                const float* __restrict__ W2i, const float* __restrict__ W2h,
                const float* __restrict__ b2i, const float* __restrict__ b2h,
                const float* __restrict__ eW,  const float* __restrict__ eb,
                const float* __restrict__ D1i, const float* __restrict__ D1bi,
                const float* __restrict__ D1bh,
                const float* __restrict__ D2i, const float* __restrict__ D2bi,
                const float* __restrict__ D2bh,
                const float* __restrict__ dW,  const float* __restrict__ db,
                float* __restrict__ out)
{
    __shared__ uint32_t h1L[4][32];  // h1 per sample, f16 pairs
    __shared__ uint32_t h2L[4][32];  // h2 per sample, f16 pairs
    __shared__ float pre1[4][260];   // layer-1 preacts [sample][row] (+pad)
    __shared__ float pre2[4][260];   // layer-2 preacts
    __shared__ float uL[4][8];

    const int tid = threadIdx.x;
    const int blk = blockIdx.x;
    const int s  = tid >> 8;   // this thread's sample
    const int r  = tid & 255;  // gate row
    const int j  = tid & 63;   // update unit
    const int sq = tid >> 6;   // update sample (threads 0..255)

    // ---- pack this row's weights into registers (f16 pairs) ----
    uint4 w1q[8], w2q[8], w3q[8];
    #pragma unroll
    for (int k8 = 0; k8 < 8; ++k8) {
        w1q[k8] = pack8(W1h + r * 64 + k8 * 8);   // Whh1[r,:]
        w2q[k8] = pack8(W2i + r * 64 + k8 * 8);   // Wih2[r,:]
        w3q[k8] = pack8(W2h + r * 64 + k8 * 8);   // Whh2[r,:]
    }
    const float bias1 = b1i[r] + b1h[r];
    const float bias2 = b2i[r] + b2h[r];
    const float wx0 = W1i[r * 3 + 0], wx1 = W1i[r * 3 + 1], wx2 = W1i[r * 3 + 2];

    if (tid < 128) {
        h1L[tid >> 5][tid & 31] = 0u;
        h2L[tid >> 5][tid & 31] = 0u;
    }

    float c1 = 0.0f, c2 = 0.0f;  // state owned by threads 0..255

    const size_t xb = ((size_t)(blk * 4 + s) * 1024) * 3;
    float xa0 = x[xb + 0], xa1 = x[xb + 1], xa2 = x[xb + 2];

    __syncthreads();

    #pragma unroll 1
    for (int t = 0; t < 1024; ++t) {
        // ---- Phase A: layer1 matmul row r, sample s ----
        float a = bias1 + wx0 * xa0 + wx1 * xa1 + wx2 * xa2;
        #pragma unroll
        for (int k8 = 0; k8 < 8; ++k8) {
            const uint4 hv = *(const uint4*)&h1L[s][k8 * 4];
            DOT4(a, w1q[k8], hv)
        }
        pre1[s][r] = a;
        __syncthreads();

        // ---- Phase B: layer1 update (threads 0..255) + x prefetch (all) ----
        int tn = (t < 1023) ? (t + 1) : t;
        const float* q = x + xb + (size_t)tn * 3;
        float xn0 = q[0], xn1 = q[1], xn2 = q[2];
        if (tid < 256) {
            float pi = pre1[sq][j],       pf = pre1[sq][64 + j];
            float pg = pre1[sq][128 + j], po = pre1[sq][192 + j];
            c1 = sigf(pf) * c1 + sigf(pi) * tanhf_fast(pg);
            float hn = sigf(po) * tanhf_fast(c1);
            ((uint16_t*)h1L[sq])[j] = __builtin_bit_cast(uint16_t, (_Float16)hn);
        }
        __syncthreads();

        // ---- Phase C: layer2 matmul (new h1, old h2) ----
        float p = bias2;
        #pragma unroll
        for (int k8 = 0; k8 < 8; ++k8) {
            const uint4 hA = *(const uint4*)&h1L[s][k8 * 4];
            const uint4 hB = *(const uint4*)&h2L[s][k8 * 4];
            DOT4(p, w2q[k8], hA) DOT4(p, w3q[k8], hB)
        }
        pre2[s][r] = p;
        __syncthreads();

        // ---- Phase D: layer2 update (threads 0..255), no trailing barrier ----
        if (tid < 256) {
            float pi = pre2[sq][j],       pf = pre2[sq][64 + j];
            float pg = pre2[sq][128 + j], po = pre2[sq][192 + j];
            c2 = sigf(pf) * c2 + sigf(pi) * tanhf_fast(pg);
            float hn = sigf(po) * tanhf_fast(c2);
            ((uint16_t*)h2L[sq])[j] = __builtin_bit_cast(uint16_t, (_Float16)hn);
        }
        xa0 = xn0; xa1 = xn1; xa2 = xn2;
        // hazards: D writes h2L -> next read of h2L is next C (after 2 barriers);
        // D reads pre2 -> next write of pre2 is next C; next A touches pre1/h1L only.
    }
    __syncthreads();

    // ---- Decoder tail: threads 0..255, wave sq handles sample S ----
    const int S = blk * 4 + sq;

    // u = enc_fc(h2_final)
    if (tid < 256 && j < 5) {
        float acc = eb[j];
        const uint16_t* hh = (const uint16_t*)h2L[sq];
        for (int k = 0; k < 64; ++k) acc += eW[j * 64 + k] * f16u(hh[k]);
        uL[sq][j] = acc;
        out[S * 5 + j] = acc;
    }
    __syncthreads();

    // d1: single step from zero state -> only gates i(0), g(2), o(3) matter
    if (tid < 256) {
        float u0 = uL[sq][0], u1 = uL[sq][1], u2 = uL[sq][2], u3 = uL[sq][3], u4 = uL[sq][4];
        int ri = j, rg = 128 + j, ro = 192 + j;
        float pi = D1bi[ri] + D1bh[ri];
        float pg = D1bi[rg] + D1bh[rg];
        float po = D1bi[ro] + D1bh[ro];
        pi += D1i[ri*5+0]*u0 + D1i[ri*5+1]*u1 + D1i[ri*5+2]*u2 + D1i[ri*5+3]*u3 + D1i[ri*5+4]*u4;
        pg += D1i[rg*5+0]*u0 + D1i[rg*5+1]*u1 + D1i[rg*5+2]*u2 + D1i[rg*5+3]*u3 + D1i[rg*5+4]*u4;
        po += D1i[ro*5+0]*u0 + D1i[ro*5+1]*u1 + D1i[ro*5+2]*u2 + D1i[ro*5+3]*u3 + D1i[ro*5+4]*u4;
        float cd = sigf(pi) * tanhf_fast(pg);
        float hd = sigf(po) * tanhf_fast(cd);
        pre1[sq][j] = hd;
    }
    __syncthreads();

    // d2: single step from zero state
    if (tid < 256) {
        int ri = j, rg = 128 + j, ro = 192 + j;
        float pi = D2bi[ri] + D2bh[ri];
        float pg = D2bi[rg] + D2bh[rg];
        float po = D2bi[ro] + D2bh[ro];
        for (int k = 0; k < 64; ++k) {
            float hk = pre1[sq][k];
            pi += D2i[ri * 64 + k] * hk;
            pg += D2i[rg * 64 + k] * hk;
            po += D2i[ro * 64 + k] * hk;
        }
        float cd = sigf(pi) * tanhf_fast(pg);
        float hd = sigf(po) * tanhf_fast(cd);
        pre1[sq][128 + j] = hd;
    }
    __syncthreads();

    // tau = dec_fc(h_d2)
    if (tid < 256 && j < 3) {
        float acc = db[j];
        for (int k = 0; k < 64; ++k) acc += dW[j * 64 + k] * pre1[sq][128 + k];
        out[5120 + S * 3 + j] = acc;
    }
}

extern "C" void kernel_launch(void* const* d_in, const int* in_sizes, int n_in,
                              void* d_out, int out_size, void* d_ws, size_t ws_size,
                              hipStream_t stream) {
    (void)in_sizes; (void)n_in; (void)out_size; (void)d_ws; (void)ws_size;
    const float* x    = (const float*)d_in[0];
    const float* W1i  = (const float*)d_in[1];
    const float* W1h  = (const float*)d_in[2];
    const float* b1i  = (const float*)d_in[3];
    const float* b1h  = (const float*)d_in[4];
    const float* W2i  = (const float*)d_in[5];
    const float* W2h  = (const float*)d_in[6];
    const float* b2i  = (const float*)d_in[7];
    const float* b2h  = (const float*)d_in[8];
    const float* eW   = (const float*)d_in[9];
    const float* eb   = (const float*)d_in[10];
    const float* D1i  = (const float*)d_in[11];
    const float* D1bi = (const float*)d_in[13];
    const float* D1bh = (const float*)d_in[14];
    const float* D2i  = (const float*)d_in[15];
    const float* D2bi = (const float*)d_in[17];
    const float* D2bh = (const float*)d_in[18];
    const float* dW   = (const float*)d_in[19];
    const float* db   = (const float*)d_in[20];

    hipLaunchKernelGGL(lstm_fused, dim3(256), dim3(1024), 0, stream,
                       x, W1i, W1h, b1i, b1h, W2i, W2h, b2i, b2h, eW, eb,
                       D1i, D1bi, D1bh, D2i, D2bi, D2bh, dW, db,
                       (float*)d_out);
}

// Round 6
// 1988.171 us; speedup vs baseline: 2.4062x; 2.4062x over previous
//
#include <hip/hip_runtime.h>
#include <stdint.h>

typedef _Float16 half2v __attribute__((ext_vector_type(2)));

__device__ __forceinline__ float sigf(float x) {
    return __builtin_amdgcn_rcpf(1.0f + __expf(-x));
}
__device__ __forceinline__ float tanhf_fast(float x) {
    return 1.0f - 2.0f * __builtin_amdgcn_rcpf(1.0f + __expf(2.0f * x));
}
__device__ __forceinline__ uint32_t pk2(float a, float b) {
    uint16_t ua = __builtin_bit_cast(uint16_t, (_Float16)a);
    uint16_t ub = __builtin_bit_cast(uint16_t, (_Float16)b);
    return (uint32_t)ua | ((uint32_t)ub << 16);
}
__device__ __forceinline__ float f16u(uint16_t b) {
    return (float)__builtin_bit_cast(_Float16, b);
}
__device__ __forceinline__ float dot2(uint32_t w, uint32_t h, float acc) {
#if __has_builtin(__builtin_amdgcn_fdot2)
    return __builtin_amdgcn_fdot2(__builtin_bit_cast(half2v, w),
                                  __builtin_bit_cast(half2v, h), acc, false);
#else
    asm("v_fma_mix_f32 %0, %1, %2, %0 op_sel:[0,0,0] op_sel_hi:[1,1,0]"
        : "+v"(acc) : "v"(w), "v"(h));
    asm("v_fma_mix_f32 %0, %1, %2, %0 op_sel:[1,1,0] op_sel_hi:[1,1,0]"
        : "+v"(acc) : "v"(w), "v"(h));
    return acc;
#endif
}

#define DOT4(acc, wv, hv)            \
    acc = dot2(wv.x, hv.x, acc);     \
    acc = dot2(wv.y, hv.y, acc);     \
    acc = dot2(wv.z, hv.z, acc);     \
    acc = dot2(wv.w, hv.w, acc);

__device__ __forceinline__ uint4 pack8(const float* s) {
    uint4 p;
    p.x = pk2(s[0], s[1]); p.y = pk2(s[2], s[3]);
    p.z = pk2(s[4], s[5]); p.w = pk2(s[6], s[7]);
    return p;
}

// Fused 2-layer LSTM encoder (persistent, T=1024) + decoder tail.
// grid = 512 blocks (2/CU), block = 512 thr (8 waves) -> 16 waves/CU = 4/SIMD.
// EMPIRICAL (R2/R4/R5 counters): 1024-thr blocks get VGPR pinned to 64 (spill);
// 512-thr blocks allow ~120 VGPR. So 4 waves/SIMD must come from 2x 512-blocks.
// Thread (s = tid>>8, r = tid&255) owns gate row r's weights IN REGISTERS and
// computes row r of sample s (96 dot2/step). Update: threads 0..127,
// (j = tid&63, sq = tid>>6) own unit j of sample sq. 3 barriers/step.
__global__ __launch_bounds__(512, 2)
void lstm_fused(const float* __restrict__ x,
                const float* __restrict__ W1i, const float* __restrict__ W1h,
                const float* __restrict__ b1i, const float* __restrict__ b1h,
                const float* __restrict__ W2i, const float* __restrict__ W2h,
                const float* __restrict__ b2i, const float* __restrict__ b2h,
                const float* __restrict__ eW,  const float* __restrict__ eb,
                const float* __restrict__ D1i, const float* __restrict__ D1bi,
                const float* __restrict__ D1bh,
                const float* __restrict__ D2i, const float* __restrict__ D2bi,
                const float* __restrict__ D2bh,
                const float* __restrict__ dW,  const float* __restrict__ db,
                float* __restrict__ out)
{
    __shared__ uint32_t h1L[2][32];  // h1 per sample, f16 pairs
    __shared__ uint32_t h2L[2][32];  // h2 per sample, f16 pairs
    __shared__ float pre1[2][260];   // layer-1 preacts [sample][row] (+pad)
    __shared__ float pre2[2][260];   // layer-2 preacts
    __shared__ float uL[2][8];

    const int tid = threadIdx.x;
    const int blk = blockIdx.x;
    const int s  = tid >> 8;   // this thread's sample (0/1)
    const int r  = tid & 255;  // gate row
    const int j  = tid & 63;   // update unit
    const int sq = tid >> 6;   // update sample (threads 0..127)

    // ---- pack this row's weights into registers (f16 pairs), 96 VGPRs ----
    uint4 w1q[8], w2q[8], w3q[8];
    #pragma unroll
    for (int k8 = 0; k8 < 8; ++k8) {
        w1q[k8] = pack8(W1h + r * 64 + k8 * 8);   // Whh1[r,:]
        w2q[k8] = pack8(W2i + r * 64 + k8 * 8);   // Wih2[r,:]
        w3q[k8] = pack8(W2h + r * 64 + k8 * 8);   // Whh2[r,:]
    }
    const float bias1 = b1i[r] + b1h[r];
    const float bias2 = b2i[r] + b2h[r];
    const float wx0 = W1i[r * 3 + 0], wx1 = W1i[r * 3 + 1], wx2 = W1i[r * 3 + 2];

    if (tid < 64) {
        h1L[tid >> 5][tid & 31] = 0u;
        h2L[tid >> 5][tid & 31] = 0u;
    }

    float c1 = 0.0f, c2 = 0.0f;  // state owned by threads 0..127

    const size_t xb = ((size_t)(blk * 2 + s) * 1024) * 3;
    float xa0 = x[xb + 0], xa1 = x[xb + 1], xa2 = x[xb + 2];

    __syncthreads();

    #pragma unroll 1
    for (int t = 0; t < 1024; ++t) {
        // ---- Phase A: layer1 matmul row r, sample s ----
        float a = bias1 + wx0 * xa0 + wx1 * xa1 + wx2 * xa2;
        #pragma unroll
        for (int k8 = 0; k8 < 8; ++k8) {
            const uint4 hv = *(const uint4*)&h1L[s][k8 * 4];  // wave-uniform broadcast
            DOT4(a, w1q[k8], hv)
        }
        pre1[s][r] = a;
        __syncthreads();

        // ---- Phase B: layer1 update (threads 0..127) + x prefetch (all) ----
        int tn = (t < 1023) ? (t + 1) : t;
        const float* q = x + xb + (size_t)tn * 3;
        float xn0 = q[0], xn1 = q[1], xn2 = q[2];
        if (tid < 128) {
            float pi = pre1[sq][j],       pf = pre1[sq][64 + j];
            float pg = pre1[sq][128 + j], po = pre1[sq][192 + j];
            c1 = sigf(pf) * c1 + sigf(pi) * tanhf_fast(pg);
            float hn = sigf(po) * tanhf_fast(c1);
            ((uint16_t*)h1L[sq])[j] = __builtin_bit_cast(uint16_t, (_Float16)hn);
        }
        __syncthreads();

        // ---- Phase C: layer2 matmul (new h1, old h2) ----
        float p = bias2;
        #pragma unroll
        for (int k8 = 0; k8 < 8; ++k8) {
            const uint4 hA = *(const uint4*)&h1L[s][k8 * 4];
            const uint4 hB = *(const uint4*)&h2L[s][k8 * 4];
            DOT4(p, w2q[k8], hA) DOT4(p, w3q[k8], hB)
        }
        pre2[s][r] = p;
        __syncthreads();

        // ---- Phase D: layer2 update (threads 0..127), no trailing barrier ----
        if (tid < 128) {
            float pi = pre2[sq][j],       pf = pre2[sq][64 + j];
            float pg = pre2[sq][128 + j], po = pre2[sq][192 + j];
            c2 = sigf(pf) * c2 + sigf(pi) * tanhf_fast(pg);
            float hn = sigf(po) * tanhf_fast(c2);
            ((uint16_t*)h2L[sq])[j] = __builtin_bit_cast(uint16_t, (_Float16)hn);
        }
        xa0 = xn0; xa1 = xn1; xa2 = xn2;
        // hazard audit: D writes h2L -> next h2L read is C' (bar1',bar2' between);
        // D reads pre2 -> pre2 next written in C' (bar3..bar2' between);
        // A' writes pre1 -> pre1 last read in B (bar2 between). All cross >=1 barrier.
    }
    __syncthreads();

    // ---- Decoder tail: threads 0..127, (sq, j) handles sample S ----
    const int S = blk * 2 + sq;

    // u = enc_fc(h2_final)
    if (tid < 128 && j < 5) {
        float acc = eb[j];
        const uint16_t* hh = (const uint16_t*)h2L[sq];
        for (int k = 0; k < 64; ++k) acc += eW[j * 64 + k] * f16u(hh[k]);
        uL[sq][j] = acc;
        out[S * 5 + j] = acc;
    }
    __syncthreads();

    // d1: single step from zero state -> only gates i(0), g(2), o(3) matter
    if (tid < 128) {
        float u0 = uL[sq][0], u1 = uL[sq][1], u2 = uL[sq][2], u3 = uL[sq][3], u4 = uL[sq][4];
        int ri = j, rg = 128 + j, ro = 192 + j;
        float pi = D1bi[ri] + D1bh[ri];
        float pg = D1bi[rg] + D1bh[rg];
        float po = D1bi[ro] + D1bh[ro];
        pi += D1i[ri*5+0]*u0 + D1i[ri*5+1]*u1 + D1i[ri*5+2]*u2 + D1i[ri*5+3]*u3 + D1i[ri*5+4]*u4;
        pg += D1i[rg*5+0]*u0 + D1i[rg*5+1]*u1 + D1i[rg*5+2]*u2 + D1i[rg*5+3]*u3 + D1i[rg*5+4]*u4;
        po += D1i[ro*5+0]*u0 + D1i[ro*5+1]*u1 + D1i[ro*5+2]*u2 + D1i[ro*5+3]*u3 + D1i[ro*5+4]*u4;
        float cd = sigf(pi) * tanhf_fast(pg);
        float hd = sigf(po) * tanhf_fast(cd);
        pre1[sq][j] = hd;
    }
    __syncthreads();

    // d2: single step from zero state
    if (tid < 128) {
        int ri = j, rg = 128 + j, ro = 192 + j;
        float pi = D2bi[ri] + D2bh[ri];
        float pg = D2bi[rg] + D2bh[rg];
        float po = D2bi[ro] + D2bh[ro];
        for (int k = 0; k < 64; ++k) {
            float hk = pre1[sq][k];
            pi += D2i[ri * 64 + k] * hk;
            pg += D2i[rg * 64 + k] * hk;
            po += D2i[ro * 64 + k] * hk;
        }
        float cd = sigf(pi) * tanhf_fast(pg);
        float hd = sigf(po) * tanhf_fast(cd);
        pre1[sq][128 + j] = hd;
    }
    __syncthreads();

    // tau = dec_fc(h_d2)
    if (tid < 128 && j < 3) {
        float acc = db[j];
        for (int k = 0; k < 64; ++k) acc += dW[j * 64 + k] * pre1[sq][128 + k];
        out[5120 + S * 3 + j] = acc;
    }
}

extern "C" void kernel_launch(void* const* d_in, const int* in_sizes, int n_in,
                              void* d_out, int out_size, void* d_ws, size_t ws_size,
                              hipStream_t stream) {
    (void)in_sizes; (void)n_in; (void)out_size; (void)d_ws; (void)ws_size;
    const float* x    = (const float*)d_in[0];
    const float* W1i  = (const float*)d_in[1];
    const float* W1h  = (const float*)d_in[2];
    const float* b1i  = (const float*)d_in[3];
    const float* b1h  = (const float*)d_in[4];
    const float* W2i  = (const float*)d_in[5];
    const float* W2h  = (const float*)d_in[6];
    const float* b2i  = (const float*)d_in[7];
    const float* b2h  = (const float*)d_in[8];
    const float* eW   = (const float*)d_in[9];
    const float* eb   = (const float*)d_in[10];
    const float* D1i  = (const float*)d_in[11];
    const float* D1bi = (const float*)d_in[13];
    const float* D1bh = (const float*)d_in[14];
    const float* D2i  = (const float*)d_in[15];
    const float* D2bi = (const float*)d_in[17];
    const float* D2bh = (const float*)d_in[18];
    const float* dW   = (const float*)d_in[19];
    const float* db   = (const float*)d_in[20];

    hipLaunchKernelGGL(lstm_fused, dim3(512), dim3(512), 0, stream,
                       x, W1i, W1h, b1i, b1h, W2i, W2h, b2i, b2h, eW, eb,
                       D1i, D1bi, D1bh, D2i, D2bi, D2bh, dW, db,
                       (float*)d_out);
}

// Round 7
// 910.095 us; speedup vs baseline: 5.2566x; 2.1846x over previous
//
#include <hip/hip_runtime.h>
#include <stdint.h>

typedef _Float16 f16x8 __attribute__((ext_vector_type(8)));
typedef float f32x4 __attribute__((ext_vector_type(4)));

__device__ __forceinline__ float sigf(float x) {
    return __builtin_amdgcn_rcpf(1.0f + __expf(-x));
}
__device__ __forceinline__ float tanhf_fast(float x) {
    return 1.0f - 2.0f * __builtin_amdgcn_rcpf(1.0f + __expf(2.0f * x));
}

// Fused 2-layer LSTM encoder via MFMA + decoder tail.
// grid = 256 (1 block/CU), block = 512 (8 waves, 2/SIMD).
// Waves 0-3: layer-1 gates, step t.  Waves 4-7: layer-2 gates, step t-1
// (software pipeline; h1 double-buffered in LDS).
// Gate matmul as mfma_f32_16x16x32_f16: M=16 (units 16w..16w+15 per wave,
// one tile per gate), N=16 (4 real samples, cols 4-15 zero), K=96 (L1:
// [Whh1|Wih1|0], x injected at k=64..66) / K=128 (L2: [Wih2|Whh2]).
// A-frags (weights) packed once into VGPRs; identical (lane,i)->k map used
// for A and B so any hw k-permutation cancels. C/D: col=lane&15,
// row=(lane>>4)*4+reg (verified layout). Update phase: per-wave LDS
// transpose so each lane runs the sigmoid/tanh chain for ONE (unit,col).
__global__ __launch_bounds__(512, 1)
void lstm_mfma(const float* __restrict__ x,
               const float* __restrict__ W1i, const float* __restrict__ W1h,
               const float* __restrict__ b1i, const float* __restrict__ b1h,
               const float* __restrict__ W2i, const float* __restrict__ W2h,
               const float* __restrict__ b2i, const float* __restrict__ b2h,
               const float* __restrict__ eW,  const float* __restrict__ eb,
               const float* __restrict__ D1i, const float* __restrict__ D1bi,
               const float* __restrict__ D1bh,
               const float* __restrict__ D2i, const float* __restrict__ D2bi,
               const float* __restrict__ D2bh,
               const float* __restrict__ dW,  const float* __restrict__ db,
               float* __restrict__ out)
{
    // col stride 104 f16 = 208 B (13*16: aligned, bank-spread). k: 0..63 h1,
    // 64..66 x, 67..95 zero pad (K=96 MFMA), 96..103 alignment pad.
    __shared__ __align__(16) _Float16 h1b[2][16][104];
    // col stride 72 f16 = 144 B. k: 0..63 h2, tail pad.
    __shared__ __align__(16) _Float16 h2b[16][72];
    __shared__ __align__(16) float preX[8][4][4][16]; // [wave][gate][col][unit]
    __shared__ float uL[4][8];
    __shared__ float tl1[4][64];
    __shared__ float tl2[4][64];

    const int tid = threadIdx.x, blk = blockIdx.x;
    const int wid = tid >> 6, lane = tid & 63;
    const int rl = lane & 15, hi = lane >> 4;
    const bool isL1 = (wid < 4);
    const int w = isL1 ? wid : wid - 4;   // unit-group: units [16w, 16w+16)

    // ---- zero h buffers (cols 4-15 and k-pads must stay 0 forever) ----
    {
        uint32_t* z1 = (uint32_t*)&h1b[0][0][0];
        for (int i = tid; i < 1664; i += 512) z1[i] = 0u;
        uint32_t* z2 = (uint32_t*)&h2b[0][0];
        for (int i = tid; i < 576; i += 512) z2[i] = 0u;
    }

    // ---- pack A-frags (weights, f16) into registers ----
    // A mapping assumed: row = lane&15 (within 16-row tile), k = s*32 + hi*8 + i.
    f16x8 afr[4][4];
    #pragma unroll
    for (int g = 0; g < 4; ++g) {
        const int grow = g * 64 + w * 16 + rl;  // global gate-row
        if (isL1) {
            #pragma unroll
            for (int s = 0; s < 2; ++s) {
                f16x8 v;
                #pragma unroll
                for (int i = 0; i < 8; ++i)
                    v[i] = (_Float16)W1h[grow * 64 + s * 32 + hi * 8 + i];
                afr[g][s] = v;
            }
            {
                f16x8 v;
                #pragma unroll
                for (int i = 0; i < 8; ++i) {
                    int kk = hi * 8 + i;
                    v[i] = (kk < 3) ? (_Float16)W1i[grow * 3 + kk] : (_Float16)0.0f;
                }
                afr[g][2] = v;
            }
            {
                f16x8 v;
                #pragma unroll
                for (int i = 0; i < 8; ++i) v[i] = (_Float16)0.0f;
                afr[g][3] = v;
            }
        } else {
            #pragma unroll
            for (int s = 0; s < 2; ++s) {
                f16x8 v;
                #pragma unroll
                for (int i = 0; i < 8; ++i)
                    v[i] = (_Float16)W2i[grow * 64 + s * 32 + hi * 8 + i];
                afr[g][s] = v;
            }
            #pragma unroll
            for (int s = 0; s < 2; ++s) {
                f16x8 v;
                #pragma unroll
                for (int i = 0; i < 8; ++i)
                    v[i] = (_Float16)W2h[grow * 64 + s * 32 + hi * 8 + i];
                afr[g][2 + s] = v;
            }
        }
    }

    // ---- biases into accumulator-init regs (C/D row = hi*4 + r) ----
    f32x4 bias[4];
    #pragma unroll
    for (int g = 0; g < 4; ++g) {
        #pragma unroll
        for (int r = 0; r < 4; ++r) {
            int grow = g * 64 + w * 16 + hi * 4 + r;
            bias[g][r] = isL1 ? (b1i[grow] + b1h[grow]) : (b2i[grow] + b2h[grow]);
        }
    }

    float cst = 0.0f;  // c-state for (unit 16w + rl, sample hi), per lane

    __syncthreads();
    // prestage x(0) into buf 0
    if (wid == 0 && lane < 4) {
        const float* xp = x + (size_t)(blk * 4 + lane) * 3072;
        h1b[0][lane][64] = (_Float16)xp[0];
        h1b[0][lane][65] = (_Float16)xp[1];
        h1b[0][lane][66] = (_Float16)xp[2];
    }
    __syncthreads();

    #pragma unroll 1
    for (int t = 0; t <= 1024; ++t) {
        const int p = t & 1;                 // h1(t-1) lives in buf p
        const bool doL1 = isL1 && (t < 1024);
        const bool doL2 = (!isL1) && (t >= 1);

        // ---- phase 1: gate matmuls ----
        if (doL1) {
            f32x4 a0 = bias[0], a1 = bias[1], a2 = bias[2], a3 = bias[3];
            #pragma unroll
            for (int s = 0; s < 3; ++s) {
                f16x8 bf = *(const f16x8*)&h1b[p][rl][s * 32 + hi * 8];
                a0 = __builtin_amdgcn_mfma_f32_16x16x32_f16(afr[0][s], bf, a0, 0, 0, 0);
                a1 = __builtin_amdgcn_mfma_f32_16x16x32_f16(afr[1][s], bf, a1, 0, 0, 0);
                a2 = __builtin_amdgcn_mfma_f32_16x16x32_f16(afr[2][s], bf, a2, 0, 0, 0);
                a3 = __builtin_amdgcn_mfma_f32_16x16x32_f16(afr[3][s], bf, a3, 0, 0, 0);
            }
            if (rl < 4) {
                *(f32x4*)&preX[wid][0][rl][hi * 4] = a0;
                *(f32x4*)&preX[wid][1][rl][hi * 4] = a1;
                *(f32x4*)&preX[wid][2][rl][hi * 4] = a2;
                *(f32x4*)&preX[wid][3][rl][hi * 4] = a3;
            }
        } else if (doL2) {
            f32x4 a0 = bias[0], a1 = bias[1], a2 = bias[2], a3 = bias[3];
            #pragma unroll
            for (int s = 0; s < 2; ++s) {   // K 0..63: Wih2 x h1(t-1)
                f16x8 bf = *(const f16x8*)&h1b[p][rl][s * 32 + hi * 8];
                a0 = __builtin_amdgcn_mfma_f32_16x16x32_f16(afr[0][s], bf, a0, 0, 0, 0);
                a1 = __builtin_amdgcn_mfma_f32_16x16x32_f16(afr[1][s], bf, a1, 0, 0, 0);
                a2 = __builtin_amdgcn_mfma_f32_16x16x32_f16(afr[2][s], bf, a2, 0, 0, 0);
                a3 = __builtin_amdgcn_mfma_f32_16x16x32_f16(afr[3][s], bf, a3, 0, 0, 0);
            }
            #pragma unroll
            for (int s = 0; s < 2; ++s) {   // K 64..127: Whh2 x h2(t-2)
                f16x8 bf = *(const f16x8*)&h2b[rl][s * 32 + hi * 8];
                a0 = __builtin_amdgcn_mfma_f32_16x16x32_f16(afr[0][2 + s], bf, a0, 0, 0, 0);
                a1 = __builtin_amdgcn_mfma_f32_16x16x32_f16(afr[1][2 + s], bf, a1, 0, 0, 0);
                a2 = __builtin_amdgcn_mfma_f32_16x16x32_f16(afr[2][2 + s], bf, a2, 0, 0, 0);
                a3 = __builtin_amdgcn_mfma_f32_16x16x32_f16(afr[3][2 + s], bf, a3, 0, 0, 0);
            }
            if (rl < 4) {
                *(f32x4*)&preX[wid][0][rl][hi * 4] = a0;
                *(f32x4*)&preX[wid][1][rl][hi * 4] = a1;
                *(f32x4*)&preX[wid][2][rl][hi * 4] = a2;
                *(f32x4*)&preX[wid][3][rl][hi * 4] = a3;
            }
        }
        __syncthreads();

        // ---- phase 2: LSTM update, one (unit,col) per lane ----
        if (doL1 || doL2) {
            float pi  = preX[wid][0][hi][rl];
            float pf  = preX[wid][1][hi][rl];
            float pgg = preX[wid][2][hi][rl];
            float po  = preX[wid][3][hi][rl];
            cst = sigf(pf) * cst + sigf(pi) * tanhf_fast(pgg);
            float hn = sigf(po) * tanhf_fast(cst);
            if (doL1) h1b[p ^ 1][hi][w * 16 + rl] = (_Float16)hn;
            else      h2b[hi][w * 16 + rl] = (_Float16)hn;
        }
        // stage x(t+1) into the buffer L1 reads next iteration
        if (wid == 0 && lane < 4 && (t + 1) < 1024) {
            const float* xp = x + (size_t)(blk * 4 + lane) * 3072 + (size_t)(t + 1) * 3;
            h1b[p ^ 1][lane][64] = (_Float16)xp[0];
            h1b[p ^ 1][lane][65] = (_Float16)xp[1];
            h1b[p ^ 1][lane][66] = (_Float16)xp[2];
        }
        __syncthreads();
    }

    // ---- decoder tail: threads 0..255, wave wid = sample ----
    const int S = blk * 4 + wid;
    if (tid < 256 && lane < 5) {
        float acc = eb[lane];
        for (int k = 0; k < 64; ++k) acc += eW[lane * 64 + k] * (float)h2b[wid][k];
        uL[wid][lane] = acc;
        out[S * 5 + lane] = acc;
    }
    __syncthreads();

    if (tid < 256) {  // d1: single step from zero state (only i, g, o gates)
        float u0 = uL[wid][0], u1 = uL[wid][1], u2 = uL[wid][2], u3 = uL[wid][3], u4 = uL[wid][4];
        int ri = lane, rg = 128 + lane, ro = 192 + lane;
        float pi = D1bi[ri] + D1bh[ri];
        float pg = D1bi[rg] + D1bh[rg];
        float po = D1bi[ro] + D1bh[ro];
        pi += D1i[ri*5+0]*u0 + D1i[ri*5+1]*u1 + D1i[ri*5+2]*u2 + D1i[ri*5+3]*u3 + D1i[ri*5+4]*u4;
        pg += D1i[rg*5+0]*u0 + D1i[rg*5+1]*u1 + D1i[rg*5+2]*u2 + D1i[rg*5+3]*u3 + D1i[rg*5+4]*u4;
        po += D1i[ro*5+0]*u0 + D1i[ro*5+1]*u1 + D1i[ro*5+2]*u2 + D1i[ro*5+3]*u3 + D1i[ro*5+4]*u4;
        float cd = sigf(pi) * tanhf_fast(pg);
        float hd = sigf(po) * tanhf_fast(cd);
        tl1[wid][lane] = hd;
    }
    __syncthreads();

    if (tid < 256) {  // d2: single step from zero state
        int ri = lane, rg = 128 + lane, ro = 192 + lane;
        float pi = D2bi[ri] + D2bh[ri];
        float pg = D2bi[rg] + D2bh[rg];
        float po = D2bi[ro] + D2bh[ro];
        for (int k = 0; k < 64; ++k) {
            float hk = tl1[wid][k];
            pi += D2i[ri * 64 + k] * hk;
            pg += D2i[rg * 64 + k] * hk;
            po += D2i[ro * 64 + k] * hk;
        }
        float cd = sigf(pi) * tanhf_fast(pg);
        float hd = sigf(po) * tanhf_fast(cd);
        tl2[wid][lane] = hd;
    }
    __syncthreads();

    if (tid < 256 && lane < 3) {
        float acc = db[lane];
        for (int k = 0; k < 64; ++k) acc += dW[lane * 64 + k] * tl2[wid][k];
        out[5120 + S * 3 + lane] = acc;
    }
}

extern "C" void kernel_launch(void* const* d_in, const int* in_sizes, int n_in,
                              void* d_out, int out_size, void* d_ws, size_t ws_size,
                              hipStream_t stream) {
    (void)in_sizes; (void)n_in; (void)out_size; (void)d_ws; (void)ws_size;
    const float* x    = (const float*)d_in[0];
    const float* W1i  = (const float*)d_in[1];
    const float* W1h  = (const float*)d_in[2];
    const float* b1i  = (const float*)d_in[3];
    const float* b1h  = (const float*)d_in[4];
    const float* W2i  = (const float*)d_in[5];
    const float* W2h  = (const float*)d_in[6];
    const float* b2i  = (const float*)d_in[7];
    const float* b2h  = (const float*)d_in[8];
    const float* eW   = (const float*)d_in[9];
    const float* eb   = (const float*)d_in[10];
    const float* D1i  = (const float*)d_in[11];
    const float* D1bi = (const float*)d_in[13];
    const float* D1bh = (const float*)d_in[14];
    const float* D2i  = (const float*)d_in[15];
    const float* D2bi = (const float*)d_in[17];
    const float* D2bh = (const float*)d_in[18];
    const float* dW   = (const float*)d_in[19];
    const float* db   = (const float*)d_in[20];

    hipLaunchKernelGGL(lstm_mfma, dim3(256), dim3(512), 0, stream,
                       x, W1i, W1h, b1i, b1h, W2i, W2h, b2i, b2h, eW, eb,
                       D1i, D1bi, D1bh, D2i, D2bi, D2bh, dW, db,
                       (float*)d_out);
}